// Round 1
// baseline (67.437 us; speedup 1.0000x reference)
//
#include <hip/hip_runtime.h>

// conv1: t4[k(8), o(4), m(28), n(28)] = sum_{i<64, j<3} w1[k,i,j] * tap(i,o,j,m,n)
// tap = x[(i*4+o), (m+j-2) mod 28, n], zero when m+j==0 or m+j==29.
__global__ __launch_bounds__(256) void conv1_kernel(const float* __restrict__ x,
                                                    const float* __restrict__ w1,
                                                    float* __restrict__ t4) {
    const int k = blockIdx.y;               // 0..7 (conv1 out channel)
    __shared__ float w1s[192];              // w1[k, :, :]
    if (threadIdx.x < 192) w1s[threadIdx.x] = w1[k * 192 + threadIdx.x];
    __syncthreads();

    const int idx = blockIdx.x * 256 + threadIdx.x;   // o*784 + m*28 + n
    if (idx >= 4 * 28 * 28) return;
    const int n = idx % 28;
    const int m = (idx / 28) % 28;
    const int o = idx / 784;

    float acc = 0.f;
#pragma unroll
    for (int j = 0; j < 3; ++j) {
        const int mj = m + j;
        if (mj == 0 || mj == 29) continue;       // zero pad rows
        int hh = mj - 2;
        if (hh < 0) hh += 28;                    // roll wrap: -1 -> 27
        const float* xp = x + o * 784 + hh * 28 + n;   // channel c = i*4+o
#pragma unroll 8
        for (int i = 0; i < 64; ++i) {
            acc = fmaf(w1s[i * 3 + j], xp[i * 4 * 784], acc);
        }
    }
    t4[k * 3136 + idx] = acc;
}

// conv2: out[i(32), o(8), m, n] = sum_{j<4, k<3} w2[i,j,k] * t4[o, j, m, n+k-1]
__global__ __launch_bounds__(256) void conv2_kernel(const float* __restrict__ t4,
                                                    const float* __restrict__ w2,
                                                    float* __restrict__ out) {
    const int i = blockIdx.y;               // 0..31
    __shared__ float w2s[12];               // w2[i, :, :]
    if (threadIdx.x < 12) w2s[threadIdx.x] = w2[i * 12 + threadIdx.x];
    __syncthreads();

    const int idx = blockIdx.x * 256 + threadIdx.x;   // o*784 + m*28 + n
    if (idx >= 8 * 28 * 28) return;
    const int n = idx % 28;
    const int om = idx / 28;
    const int m = om % 28;
    const int o = om / 28;

    const float* tp = t4 + o * 3136 + m * 28;   // + j*784 inside loop
    float acc = 0.f;
#pragma unroll
    for (int j = 0; j < 4; ++j) {
#pragma unroll
        for (int k = 0; k < 3; ++k) {
            const int nn = n + k - 1;
            if (nn < 0 || nn >= 28) continue;    // zero pad cols
            acc = fmaf(w2s[j * 3 + k], tp[j * 784 + nn], acc);
        }
    }
    out[i * 6272 + idx] = acc;                   // ((i*8+o)*28+m)*28+n
}

extern "C" void kernel_launch(void* const* d_in, const int* in_sizes, int n_in,
                              void* d_out, int out_size, void* d_ws, size_t ws_size,
                              hipStream_t stream) {
    const float* x  = (const float*)d_in[0];   // (1,256,28,28)
    const float* w1 = (const float*)d_in[1];   // (8,64,3)
    const float* w2 = (const float*)d_in[2];   // (32,4,3)
    float* out = (float*)d_out;                // (1,256,28,28)
    float* t4  = (float*)d_ws;                 // 25088 floats = 100 KB scratch

    conv1_kernel<<<dim3(13, 8),  256, 0, stream>>>(x,  w1, t4);
    conv2_kernel<<<dim3(25, 32), 256, 0, stream>>>(t4, w2, out);
}